// Round 1
// baseline (348.207 us; speedup 1.0000x reference)
//
#include <hip/hip_runtime.h>

#define B_  2
#define S_  2048
#define E_  1024
#define H_  16
#define D_  64
#define NGLOB 2
#define NRAND 3
#define WIN 3

typedef __bf16 bf16x8 __attribute__((ext_vector_type(8)));
typedef float  f32x4  __attribute__((ext_vector_type(4)));

__device__ __forceinline__ unsigned short f2bf(float f) {
    unsigned u = __builtin_bit_cast(unsigned, f);
    unsigned r = u + 0x7FFFu + ((u >> 16) & 1u);   // RNE
    return (unsigned short)(r >> 16);
}
__device__ __forceinline__ float bf2f(unsigned short u) {
    return __builtin_bit_cast(float, (unsigned)u << 16);
}

// ---------------- fp32 -> bf16 conversion (vectorized) ----------------
__global__ void f32_to_bf16_k(const float* __restrict__ src,
                              unsigned short* __restrict__ dst, int n4) {
    int i = blockIdx.x * blockDim.x + threadIdx.x;
    if (i < n4) {
        float4 f = ((const float4*)src)[i];
        ushort4 u;
        u.x = f2bf(f.x); u.y = f2bf(f.y); u.z = f2bf(f.z); u.w = f2bf(f.w);
        ((ushort4*)dst)[i] = u;
    }
}

// ---------------- bias concat [3072] ----------------
__global__ void bias_concat_k(const float* __restrict__ qb, const float* __restrict__ kb,
                              const float* __restrict__ vb, float* __restrict__ dst) {
    int i = blockIdx.x * blockDim.x + threadIdx.x;
    if (i < 3 * E_) {
        float v = (i < E_) ? qb[i] : (i < 2 * E_) ? kb[i - E_] : vb[i - 2 * E_];
        dst[i] = v;
    }
}

// ---------------- bf16 GEMM: C[m][n] = sum_k A[m][k] * W[n][k] + bias[n] ----------------
// 128x128 tile, BK=32, 256 threads = 4 waves (2x2), each wave 64x64 via 4x4 mfma 16x16x32.
#define TM 128
#define TN 128
#define TK 32
#define LDA_P 40   // padded LDS row (elems): stride 80B -> conflict-free-ish

template<int WRITE_F32>
__global__ __launch_bounds__(256, 2)
void gemm_bt(const unsigned short* __restrict__ A,  // [M][K] bf16
             const unsigned short* __restrict__ W,  // [N][K] bf16
             const float* __restrict__ bias,        // [N]
             float* __restrict__ Cf, unsigned short* __restrict__ Cb,
             int M, int N, int K) {
    __shared__ unsigned short sA[TM * LDA_P];
    __shared__ unsigned short sB[TN * LDA_P];
    const int t = threadIdx.x;
    const int lane = t & 63;
    const int wave = t >> 6;
    const int wm = wave >> 1, wn = wave & 1;
    const int lq = lane >> 4;      // quad 0..3
    const int lr = lane & 15;
    const int bm = blockIdx.x * TM;
    const int bn = blockIdx.y * TN;

    const int srow = t >> 1;            // 0..127
    const int scol = (t & 1) * 16;      // 0 or 16 (elems)

    f32x4 acc[4][4] = {};

    for (int k0 = 0; k0 < K; k0 += TK) {
        // stage A and B tiles (each thread: 16 contiguous elems = 2x uint4)
        const unsigned short* Ag = A + (size_t)(bm + srow) * K + k0 + scol;
        const unsigned short* Wg = W + (size_t)(bn + srow) * K + k0 + scol;
        uint4 a0 = *(const uint4*)Ag;
        uint4 a1 = *(const uint4*)(Ag + 8);
        uint4 b0 = *(const uint4*)Wg;
        uint4 b1 = *(const uint4*)(Wg + 8);
        *(uint4*)&sA[srow * LDA_P + scol]     = a0;
        *(uint4*)&sA[srow * LDA_P + scol + 8] = a1;
        *(uint4*)&sB[srow * LDA_P + scol]     = b0;
        *(uint4*)&sB[srow * LDA_P + scol + 8] = b1;
        __syncthreads();

        bf16x8 af[4], bfr[4];
        #pragma unroll
        for (int i = 0; i < 4; ++i)
            af[i] = *(const bf16x8*)&sA[(wm * 64 + i * 16 + lr) * LDA_P + lq * 8];
        #pragma unroll
        for (int j = 0; j < 4; ++j)
            bfr[j] = *(const bf16x8*)&sB[(wn * 64 + j * 16 + lr) * LDA_P + lq * 8];
        #pragma unroll
        for (int i = 0; i < 4; ++i)
            #pragma unroll
            for (int j = 0; j < 4; ++j)
                acc[i][j] = __builtin_amdgcn_mfma_f32_16x16x32_bf16(af[i], bfr[j], acc[i][j], 0, 0, 0);
        __syncthreads();
    }

    // epilogue: D row = quad*4 + reg, col = lane&15
    #pragma unroll
    for (int i = 0; i < 4; ++i) {
        int row0 = bm + wm * 64 + i * 16 + lq * 4;
        #pragma unroll
        for (int j = 0; j < 4; ++j) {
            int col = bn + wn * 64 + j * 16 + lr;
            float bv = bias[col];
            #pragma unroll
            for (int r = 0; r < 4; ++r) {
                float v = acc[i][j][r] + bv;
                if (WRITE_F32) Cf[(size_t)(row0 + r) * N + col] = v;
                else           Cb[(size_t)(row0 + r) * N + col] = f2bf(v);
            }
        }
    }
}

// ---------------- sparse attention rows i >= 2 ----------------
// qkv: [B*S][3072] bf16 (q | k | v). attn: [B*S][1024] bf16.
__global__ __launch_bounds__(256)
void attn_sparse(const unsigned short* __restrict__ qkv,
                 const int* __restrict__ rnd,
                 unsigned short* __restrict__ attn) {
    int idx = blockIdx.x;                 // [0, B*(S-2))
    int b = idx / (S_ - 2);
    int i = idx % (S_ - 2) + 2;
    __shared__ int cols[16];
    __shared__ int ncol_s;
    __shared__ float sc[16][16];          // [h][c]
    int t = threadIdx.x;

    if (t == 0) {
        int n = 0;
        cols[n++] = 0; cols[n++] = 1;
        int lo = i - WIN; if (lo < 0) lo = 0;
        int hi = i + WIN; if (hi > S_ - 1) hi = S_ - 1;
        for (int j = lo; j <= hi; ++j) if (j >= NGLOB) cols[n++] = j;
        for (int r = 0; r < NRAND; ++r) {
            int c = rnd[i * NRAND + r];
            bool dup = false;
            for (int q = 0; q < n; ++q) dup = dup || (cols[q] == c);
            if (!dup) cols[n++] = c;
        }
        ncol_s = n;
    }
    __syncthreads();
    int n = ncol_s;

    if (t < H_ * n) {
        int h = t / n, c = t - h * n;
        const unsigned short* qp = qkv + (size_t)(b * S_ + i) * 3072 + h * D_;
        const unsigned short* kp = qkv + (size_t)(b * S_ + cols[c]) * 3072 + E_ + h * D_;
        float s = 0.f;
        #pragma unroll
        for (int d = 0; d < D_; ++d) s += bf2f(qp[d]) * bf2f(kp[d]);
        sc[h][c] = s * 0.125f;
    }
    __syncthreads();
    if (t < H_) {
        float m = -1e30f;
        for (int c = 0; c < n; ++c) m = fmaxf(m, sc[t][c]);
        float sum = 0.f;
        for (int c = 0; c < n; ++c) { float e = __expf(sc[t][c] - m); sc[t][c] = e; sum += e; }
        float inv = 1.f / sum;
        for (int c = 0; c < n; ++c) sc[t][c] *= inv;
    }
    __syncthreads();

    int h = t >> 4, d0 = (t & 15) * 4;
    float o0 = 0, o1 = 0, o2 = 0, o3 = 0;
    for (int c = 0; c < n; ++c) {
        float p = sc[h][c];
        const unsigned short* vp = qkv + (size_t)(b * S_ + cols[c]) * 3072 + 2 * E_ + h * D_ + d0;
        o0 += p * bf2f(vp[0]); o1 += p * bf2f(vp[1]);
        o2 += p * bf2f(vp[2]); o3 += p * bf2f(vp[3]);
    }
    unsigned short* op = attn + (size_t)(b * S_ + i) * E_ + h * D_ + d0;
    op[0] = f2bf(o0); op[1] = f2bf(o1); op[2] = f2bf(o2); op[3] = f2bf(o3);
}

// ---------------- full attention for global rows i < 2 ----------------
__global__ __launch_bounds__(256)
void attn_global(const unsigned short* __restrict__ qkv,
                 unsigned short* __restrict__ attn) {
    int idx = blockIdx.x;                 // [0, B*NGLOB*H)
    int b = idx >> 5, i = (idx >> 4) & 1, h = idx & 15;
    __shared__ float qs[D_];
    __shared__ float sc[S_];
    __shared__ float red[4];
    __shared__ float outp[256];
    int t = threadIdx.x;
    const size_t base = (size_t)(b * S_) * 3072;

    if (t < D_) qs[t] = bf2f(qkv[(size_t)(b * S_ + i) * 3072 + h * D_ + t]);
    __syncthreads();

    for (int c = t; c < S_; c += 256) {
        const unsigned short* kp = qkv + base + (size_t)c * 3072 + E_ + h * D_;
        float s = 0.f;
        #pragma unroll
        for (int d = 0; d < D_; ++d) s += qs[d] * bf2f(kp[d]);
        sc[c] = s * 0.125f;
    }
    __syncthreads();

    float m = -1e30f;
    for (int c = t; c < S_; c += 256) m = fmaxf(m, sc[c]);
    #pragma unroll
    for (int o = 32; o; o >>= 1) m = fmaxf(m, __shfl_down(m, o));
    if ((t & 63) == 0) red[t >> 6] = m;
    __syncthreads();
    m = fmaxf(fmaxf(red[0], red[1]), fmaxf(red[2], red[3]));

    float sum = 0.f;
    for (int c = t; c < S_; c += 256) { float e = __expf(sc[c] - m); sc[c] = e; sum += e; }
    #pragma unroll
    for (int o = 32; o; o >>= 1) sum += __shfl_down(sum, o);
    __syncthreads();
    if ((t & 63) == 0) red[t >> 6] = sum;
    __syncthreads();
    float inv = 1.f / (red[0] + red[1] + red[2] + red[3]);

    int d = t & 63, g = t >> 6;
    float acc = 0.f;
    for (int c = g * (S_ / 4); c < (g + 1) * (S_ / 4); ++c)
        acc += sc[c] * bf2f(qkv[base + (size_t)c * 3072 + 2 * E_ + h * D_ + d]);
    outp[t] = acc * inv;
    __syncthreads();
    if (t < D_) {
        float o = outp[t] + outp[64 + t] + outp[128 + t] + outp[192 + t];
        attn[(size_t)(b * S_ + i) * E_ + h * D_ + t] = f2bf(o);
    }
}

extern "C" void kernel_launch(void* const* d_in, const int* in_sizes, int n_in,
                              void* d_out, int out_size, void* d_ws, size_t ws_size,
                              hipStream_t stream) {
    const float* x   = (const float*)d_in[0];
    const int*   rnd = (const int*)d_in[1];
    const float* qw  = (const float*)d_in[2];
    const float* qb  = (const float*)d_in[3];
    const float* kw  = (const float*)d_in[4];
    const float* kb  = (const float*)d_in[5];
    const float* vw  = (const float*)d_in[6];
    const float* vb  = (const float*)d_in[7];
    const float* ow  = (const float*)d_in[8];
    const float* ob  = (const float*)d_in[9];
    float* out = (float*)d_out;

    char* ws = (char*)d_ws;
    unsigned short* xb    = (unsigned short*)(ws);                       // 4096*1024 bf16 = 8 MB
    unsigned short* wqkv  = (unsigned short*)(ws + 8388608);             // 3072*1024 bf16 = 6 MB
    unsigned short* wo    = (unsigned short*)(ws + 14680064);            // 1024*1024 bf16 = 2 MB
    unsigned short* qkv   = (unsigned short*)(ws + 16777216);            // 4096*3072 bf16 = 24 MB
    unsigned short* attn  = (unsigned short*)(ws + 41943040);            // 4096*1024 bf16 = 8 MB
    float*          b3072 = (float*)(ws + 50331648);                     // 12 KB

    const int M = B_ * S_;   // 4096

    // conversions
    f32_to_bf16_k<<<(M * E_ / 4 + 255) / 256, 256, 0, stream>>>(x, xb, M * E_ / 4);
    f32_to_bf16_k<<<(E_ * E_ / 4 + 255) / 256, 256, 0, stream>>>(qw, wqkv,            E_ * E_ / 4);
    f32_to_bf16_k<<<(E_ * E_ / 4 + 255) / 256, 256, 0, stream>>>(kw, wqkv + E_ * E_,  E_ * E_ / 4);
    f32_to_bf16_k<<<(E_ * E_ / 4 + 255) / 256, 256, 0, stream>>>(vw, wqkv + 2 * E_ * E_, E_ * E_ / 4);
    f32_to_bf16_k<<<(E_ * E_ / 4 + 255) / 256, 256, 0, stream>>>(ow, wo, E_ * E_ / 4);
    bias_concat_k<<<(3 * E_ + 255) / 256, 256, 0, stream>>>(qb, kb, vb, b3072);

    // QKV GEMM: [4096][3072] bf16
    {
        dim3 grid(M / TM, 3 * E_ / TN);
        gemm_bt<0><<<grid, 256, 0, stream>>>(xb, wqkv, b3072, nullptr, qkv, M, 3 * E_, E_);
    }

    // attention
    attn_global<<<B_ * NGLOB * H_, 256, 0, stream>>>(qkv, attn);
    attn_sparse<<<B_ * (S_ - 2), 256, 0, stream>>>(qkv, rnd, attn);

    // O GEMM -> fp32 out
    {
        dim3 grid(M / TM, E_ / TN);
        gemm_bt<1><<<grid, 256, 0, stream>>>(attn, wo, ob, out, nullptr, M, E_, E_);
    }
}

// Round 2
// 218.337 us; speedup vs baseline: 1.5948x; 1.5948x over previous
//
#include <hip/hip_runtime.h>

#define B_  2
#define S_  2048
#define E_  1024
#define H_  16
#define D_  64
#define NGLOB 2
#define NRAND 3
#define WIN 3

typedef __bf16 bf16x8 __attribute__((ext_vector_type(8)));
typedef float  f32x4  __attribute__((ext_vector_type(4)));

__device__ __forceinline__ unsigned short f2bf(float f) {
    unsigned u = __builtin_bit_cast(unsigned, f);
    unsigned r = u + 0x7FFFu + ((u >> 16) & 1u);   // RNE
    return (unsigned short)(r >> 16);
}
__device__ __forceinline__ float bf2f(unsigned short u) {
    return __builtin_bit_cast(float, (unsigned)u << 16);
}

// ---------------- fused fp32 -> bf16 conversion for x + 4 weights ----------------
// regions (in float4 units): x = 1048576, then qw/kw/vw/ow 262144 each.
__global__ __launch_bounds__(256)
void convert_all(const float* __restrict__ x,  const float* __restrict__ qw,
                 const float* __restrict__ kw, const float* __restrict__ vw,
                 const float* __restrict__ ow,
                 unsigned short* __restrict__ xb, unsigned short* __restrict__ wqkv,
                 unsigned short* __restrict__ wo) {
    const int XN = (B_ * S_ * E_) / 4;      // 1048576
    const int WN = (E_ * E_) / 4;           // 262144
    int i = blockIdx.x * blockDim.x + threadIdx.x;
    int r, loc;
    if (i < XN) { r = 0; loc = i; }
    else        { int j = i - XN; r = 1 + (j >> 18); loc = j & (WN - 1); }
    const float* src = r == 0 ? x : r == 1 ? qw : r == 2 ? kw : r == 3 ? vw : ow;
    float4 f = ((const float4*)src)[loc];
    ushort4 u;
    u.x = f2bf(f.x); u.y = f2bf(f.y); u.z = f2bf(f.z); u.w = f2bf(f.w);
    ushort4* dst = r == 0 ? (ushort4*)xb : r == 4 ? (ushort4*)wo
                 : (ushort4*)wqkv + (size_t)(r - 1) * WN;
    dst[loc] = u;
}

// ---------------- bf16 GEMM: C[m][n] = sum_k A[m][k] * W[n][k] + bias[n] ----------------
// 128x128 tile, BK=32, 256 threads = 4 waves (2x2), each wave 64x64 via 4x4 mfma 16x16x32.
#define TM 128
#define TN 128
#define TK 32
#define LDA_P 40   // padded LDS row (elems): stride 80B

template<int WRITE_F32>
__global__ __launch_bounds__(256, 2)
void gemm_bt(const unsigned short* __restrict__ A,  // [M][K] bf16
             const unsigned short* __restrict__ W,  // [N][K] bf16
             const float* __restrict__ b0, const float* __restrict__ b1,
             const float* __restrict__ b2,          // bias per 1024-col segment
             float* __restrict__ Cf, unsigned short* __restrict__ Cb,
             int M, int N, int K) {
    __shared__ unsigned short sA[TM * LDA_P];
    __shared__ unsigned short sB[TN * LDA_P];
    const int t = threadIdx.x;
    const int lane = t & 63;
    const int wave = t >> 6;
    const int wm = wave >> 1, wn = wave & 1;
    const int lq = lane >> 4;      // quad 0..3
    const int lr = lane & 15;
    const int bm = blockIdx.x * TM;
    const int bn = blockIdx.y * TN;

    const int srow = t >> 1;            // 0..127
    const int scol = (t & 1) * 16;      // 0 or 16 (elems)

    f32x4 acc[4][4] = {};

    for (int k0 = 0; k0 < K; k0 += TK) {
        const unsigned short* Ag = A + (size_t)(bm + srow) * K + k0 + scol;
        const unsigned short* Wg = W + (size_t)(bn + srow) * K + k0 + scol;
        uint4 a0 = *(const uint4*)Ag;
        uint4 a1 = *(const uint4*)(Ag + 8);
        uint4 bb0 = *(const uint4*)Wg;
        uint4 bb1 = *(const uint4*)(Wg + 8);
        *(uint4*)&sA[srow * LDA_P + scol]     = a0;
        *(uint4*)&sA[srow * LDA_P + scol + 8] = a1;
        *(uint4*)&sB[srow * LDA_P + scol]     = bb0;
        *(uint4*)&sB[srow * LDA_P + scol + 8] = bb1;
        __syncthreads();

        bf16x8 af[4], bfr[4];
        #pragma unroll
        for (int i = 0; i < 4; ++i)
            af[i] = *(const bf16x8*)&sA[(wm * 64 + i * 16 + lr) * LDA_P + lq * 8];
        #pragma unroll
        for (int j = 0; j < 4; ++j)
            bfr[j] = *(const bf16x8*)&sB[(wn * 64 + j * 16 + lr) * LDA_P + lq * 8];
        #pragma unroll
        for (int i = 0; i < 4; ++i)
            #pragma unroll
            for (int j = 0; j < 4; ++j)
                acc[i][j] = __builtin_amdgcn_mfma_f32_16x16x32_bf16(af[i], bfr[j], acc[i][j], 0, 0, 0);
        __syncthreads();
    }

    // epilogue: D row = quad*4 + reg, col = lane&15
    #pragma unroll
    for (int i = 0; i < 4; ++i) {
        int row0 = bm + wm * 64 + i * 16 + lq * 4;
        #pragma unroll
        for (int j = 0; j < 4; ++j) {
            int col = bn + wn * 64 + j * 16 + lr;
            const float* bp = col < E_ ? b0 : (col < 2 * E_ ? b1 : b2);
            float bv = bp[col & (E_ - 1)];
            #pragma unroll
            for (int r = 0; r < 4; ++r) {
                float v = acc[i][j][r] + bv;
                if (WRITE_F32) Cf[(size_t)(row0 + r) * N + col] = v;
                else           Cb[(size_t)(row0 + r) * N + col] = f2bf(v);
            }
        }
    }
}

// ---------------- sparse attention rows i >= 2 ----------------
__global__ __launch_bounds__(256)
void attn_sparse(const unsigned short* __restrict__ qkv,
                 const int* __restrict__ rnd,
                 unsigned short* __restrict__ attn) {
    int idx = blockIdx.x;                 // [0, B*(S-2))
    int b = idx / (S_ - 2);
    int i = idx % (S_ - 2) + 2;
    __shared__ int cols[16];
    __shared__ int ncol_s;
    __shared__ float sc[16][16];          // [h][c]
    int t = threadIdx.x;

    if (t == 0) {
        int n = 0;
        cols[n++] = 0; cols[n++] = 1;
        int lo = i - WIN; if (lo < 0) lo = 0;
        int hi = i + WIN; if (hi > S_ - 1) hi = S_ - 1;
        for (int j = lo; j <= hi; ++j) if (j >= NGLOB) cols[n++] = j;
        for (int r = 0; r < NRAND; ++r) {
            int c = rnd[i * NRAND + r];
            bool dup = false;
            for (int q = 0; q < n; ++q) dup = dup || (cols[q] == c);
            if (!dup) cols[n++] = c;
        }
        ncol_s = n;
    }
    __syncthreads();
    int n = ncol_s;

    if (t < H_ * n) {
        int h = t / n, c = t - h * n;
        const unsigned short* qp = qkv + (size_t)(b * S_ + i) * 3072 + h * D_;
        const unsigned short* kp = qkv + (size_t)(b * S_ + cols[c]) * 3072 + E_ + h * D_;
        float s = 0.f;
        #pragma unroll
        for (int d = 0; d < D_; ++d) s += bf2f(qp[d]) * bf2f(kp[d]);
        sc[h][c] = s * 0.125f;
    }
    __syncthreads();
    if (t < H_) {
        float m = -1e30f;
        for (int c = 0; c < n; ++c) m = fmaxf(m, sc[t][c]);
        float sum = 0.f;
        for (int c = 0; c < n; ++c) { float e = __expf(sc[t][c] - m); sc[t][c] = e; sum += e; }
        float inv = 1.f / sum;
        for (int c = 0; c < n; ++c) sc[t][c] *= inv;
    }
    __syncthreads();

    int h = t >> 4, d0 = (t & 15) * 4;
    float o0 = 0, o1 = 0, o2 = 0, o3 = 0;
    for (int c = 0; c < n; ++c) {
        float p = sc[h][c];
        const unsigned short* vp = qkv + (size_t)(b * S_ + cols[c]) * 3072 + 2 * E_ + h * D_ + d0;
        o0 += p * bf2f(vp[0]); o1 += p * bf2f(vp[1]);
        o2 += p * bf2f(vp[2]); o3 += p * bf2f(vp[3]);
    }
    unsigned short* op = attn + (size_t)(b * S_ + i) * E_ + h * D_ + d0;
    op[0] = f2bf(o0); op[1] = f2bf(o1); op[2] = f2bf(o2); op[3] = f2bf(o3);
}

// ---------------- global rows (i < 2): phased, parallel ----------------
// tuple id: tup = b*32 + i*16 + h   (64 tuples)

// Phase A: scores[tup][c] = q . k * 0.125   (512 blocks)
__global__ __launch_bounds__(256)
void gattn_score(const unsigned short* __restrict__ qkv, float* __restrict__ gsc) {
    int tup = blockIdx.x;
    int b = tup >> 5, i = (tup >> 4) & 1, h = tup & 15;
    __shared__ float qs[D_];
    int t = threadIdx.x;
    if (t < D_) qs[t] = bf2f(qkv[(size_t)(b * S_ + i) * 3072 + h * D_ + t]);
    __syncthreads();
    int c = blockIdx.y * 256 + t;
    const bf16x8* kp = (const bf16x8*)(qkv + (size_t)(b * S_ + c) * 3072 + E_ + h * D_);
    float s = 0.f;
    #pragma unroll
    for (int w = 0; w < 8; ++w) {
        bf16x8 kv = kp[w];
        #pragma unroll
        for (int j = 0; j < 8; ++j) s += qs[w * 8 + j] * (float)kv[j];
    }
    gsc[(size_t)tup * S_ + c] = s * 0.125f;
}

// Phase B: softmax over c per tuple; zero the PV accumulator  (64 blocks)
__global__ __launch_bounds__(256)
void gattn_softmax(float* __restrict__ gsc, float* __restrict__ gacc) {
    int tup = blockIdx.x;
    int t = threadIdx.x;
    float* sc = gsc + (size_t)tup * S_;
    __shared__ float red[4];
    float vals[8];
    float m = -1e30f;
    #pragma unroll
    for (int k = 0; k < 8; ++k) { vals[k] = sc[t + 256 * k]; m = fmaxf(m, vals[k]); }
    #pragma unroll
    for (int o = 32; o; o >>= 1) m = fmaxf(m, __shfl_down(m, o));
    if ((t & 63) == 0) red[t >> 6] = m;
    __syncthreads();
    m = fmaxf(fmaxf(red[0], red[1]), fmaxf(red[2], red[3]));
    float sum = 0.f;
    #pragma unroll
    for (int k = 0; k < 8; ++k) { float e = __expf(vals[k] - m); vals[k] = e; sum += e; }
    #pragma unroll
    for (int o = 32; o; o >>= 1) sum += __shfl_down(sum, o);
    __syncthreads();
    if ((t & 63) == 0) red[t >> 6] = sum;
    __syncthreads();
    float inv = 1.f / (red[0] + red[1] + red[2] + red[3]);
    #pragma unroll
    for (int k = 0; k < 8; ++k) sc[t + 256 * k] = vals[k] * inv;
    if (t < D_) gacc[tup * D_ + t] = 0.f;
}

// Phase C: PV partial sums, coalesced V reads, atomicAdd into gacc (512 blocks)
__global__ __launch_bounds__(256)
void gattn_pv(const unsigned short* __restrict__ qkv, const float* __restrict__ gsc,
              float* __restrict__ gacc) {
    int tup = blockIdx.x, chunk = blockIdx.y;
    int b = tup >> 5, h = tup & 15;
    int t = threadIdx.x, w = t >> 6, d = t & 63;
    __shared__ float red[4][D_];
    const float* P = gsc + (size_t)tup * S_ + chunk * 256 + w * 64;
    float acc = 0.f;
    #pragma unroll 4
    for (int k = 0; k < 64; ++k) {
        int c = chunk * 256 + w * 64 + k;
        acc += P[k] * bf2f(qkv[(size_t)(b * S_ + c) * 3072 + 2 * E_ + h * D_ + d]);
    }
    red[w][d] = acc;
    __syncthreads();
    if (w == 0)
        atomicAdd(&gacc[tup * D_ + d], red[0][d] + red[1][d] + red[2][d] + red[3][d]);
}

// Phase D: finalize to bf16 attn rows (16 blocks)
__global__ __launch_bounds__(256)
void gattn_fin(const float* __restrict__ gacc, unsigned short* __restrict__ attn) {
    int gid = blockIdx.x * 256 + threadIdx.x;   // 4096
    int tup = gid >> 6, d = gid & 63;
    int b = tup >> 5, i = (tup >> 4) & 1, h = tup & 15;
    attn[(size_t)(b * S_ + i) * E_ + h * D_ + d] = f2bf(gacc[gid]);
}

extern "C" void kernel_launch(void* const* d_in, const int* in_sizes, int n_in,
                              void* d_out, int out_size, void* d_ws, size_t ws_size,
                              hipStream_t stream) {
    const float* x   = (const float*)d_in[0];
    const int*   rnd = (const int*)d_in[1];
    const float* qw  = (const float*)d_in[2];
    const float* qb  = (const float*)d_in[3];
    const float* kw  = (const float*)d_in[4];
    const float* kb  = (const float*)d_in[5];
    const float* vw  = (const float*)d_in[6];
    const float* vb  = (const float*)d_in[7];
    const float* ow  = (const float*)d_in[8];
    const float* ob  = (const float*)d_in[9];
    float* out = (float*)d_out;

    char* ws = (char*)d_ws;
    unsigned short* xb    = (unsigned short*)(ws);                       // 8 MB (dead after QKV GEMM)
    unsigned short* wqkv  = (unsigned short*)(ws + 8388608);             // 6 MB
    unsigned short* wo    = (unsigned short*)(ws + 14680064);            // 2 MB
    unsigned short* qkv   = (unsigned short*)(ws + 16777216);            // 24 MB
    unsigned short* attn  = (unsigned short*)(ws + 41943040);            // 8 MB
    // global-attn scratch overlaps dead xb region:
    float*          gsc   = (float*)(ws);                                // 64*2048*4 = 512 KB
    float*          gacc  = (float*)(ws + 524288);                       // 16 KB

    const int M = B_ * S_;   // 4096

    // conversions (1 launch)
    {
        int total4 = (M * E_ + 4 * E_ * E_) / 4;   // 2097152
        convert_all<<<total4 / 256, 256, 0, stream>>>(x, qw, kw, vw, ow, xb, wqkv, wo);
    }

    // QKV GEMM: [4096][3072] bf16
    {
        dim3 grid(M / TM, 3 * E_ / TN);
        gemm_bt<0><<<grid, 256, 0, stream>>>(xb, wqkv, qb, kb, vb, nullptr, qkv, M, 3 * E_, E_);
    }

    // global-row attention (phased)
    gattn_score<<<dim3(B_ * NGLOB * H_, S_ / 256), 256, 0, stream>>>(qkv, gsc);
    gattn_softmax<<<B_ * NGLOB * H_, 256, 0, stream>>>(gsc, gacc);
    gattn_pv<<<dim3(B_ * NGLOB * H_, S_ / 256), 256, 0, stream>>>(qkv, gsc, gacc);
    gattn_fin<<<(B_ * NGLOB * H_ * D_) / 256, 256, 0, stream>>>(gacc, attn);

    // sparse rows
    attn_sparse<<<B_ * (S_ - 2), 256, 0, stream>>>(qkv, rnd, attn);

    // O GEMM -> fp32 out
    {
        dim3 grid(M / TM, E_ / TN);
        gemm_bt<1><<<grid, 256, 0, stream>>>(attn, wo, ob, ob, ob, out, nullptr, M, E_, E_);
    }
}

// Round 3
// 198.325 us; speedup vs baseline: 1.7557x; 1.1009x over previous
//
#include <hip/hip_runtime.h>

#define B_  2
#define S_  2048
#define E_  1024
#define H_  16
#define D_  64
#define NGLOB 2
#define NRAND 3
#define WIN 3

typedef __bf16 bf16x8 __attribute__((ext_vector_type(8)));
typedef float  f32x4  __attribute__((ext_vector_type(4)));

__device__ __forceinline__ unsigned short f2bf(float f) {
    unsigned u = __builtin_bit_cast(unsigned, f);
    unsigned r = u + 0x7FFFu + ((u >> 16) & 1u);   // RNE
    return (unsigned short)(r >> 16);
}
__device__ __forceinline__ float bf2f(unsigned short u) {
    return __builtin_bit_cast(float, (unsigned)u << 16);
}

// async global->LDS 16B DMA. l must be wave-uniform; HW scatters lane*16.
__device__ __forceinline__ void g2l16(const unsigned short* g, unsigned short* l) {
    __builtin_amdgcn_global_load_lds(
        (const __attribute__((address_space(1))) unsigned*)g,
        (__attribute__((address_space(3))) unsigned*)l, 16, 0, 0);
}

// ---------------- fused fp32 -> bf16 conversion for x + 4 weights ----------------
__global__ __launch_bounds__(256)
void convert_all(const float* __restrict__ x,  const float* __restrict__ qw,
                 const float* __restrict__ kw, const float* __restrict__ vw,
                 const float* __restrict__ ow,
                 unsigned short* __restrict__ xb, unsigned short* __restrict__ wqkv,
                 unsigned short* __restrict__ wo) {
    const int XN = (B_ * S_ * E_) / 4;      // 1048576
    const int WN = (E_ * E_) / 4;           // 262144
    int i = blockIdx.x * blockDim.x + threadIdx.x;
    int r, loc;
    if (i < XN) { r = 0; loc = i; }
    else        { int j = i - XN; r = 1 + (j >> 18); loc = j & (WN - 1); }
    const float* src = r == 0 ? x : r == 1 ? qw : r == 2 ? kw : r == 3 ? vw : ow;
    float4 f = ((const float4*)src)[loc];
    ushort4 u;
    u.x = f2bf(f.x); u.y = f2bf(f.y); u.z = f2bf(f.z); u.w = f2bf(f.w);
    ushort4* dst = r == 0 ? (ushort4*)xb : r == 4 ? (ushort4*)wo
                 : (ushort4*)wqkv + (size_t)(r - 1) * WN;
    dst[loc] = u;
}

// ---------------- bf16 GEMM (m97 structure): C = A * W^T + bias ----------------
// 128x128 tile, BK=32, 256 threads = 4 waves (2x2), global_load_lds width-16 staging.
#define TM 128
#define TN 128
#define TK 32

template<int WRITE_F32>
__global__ __launch_bounds__(256, 2)
void gemm_bt(const unsigned short* __restrict__ A,  // [M][K] bf16
             const unsigned short* __restrict__ W,  // [N][K] bf16
             const float* __restrict__ b0, const float* __restrict__ b1,
             const float* __restrict__ b2,          // bias per 1024-col segment
             float* __restrict__ Cf, unsigned short* __restrict__ Cb,
             int M, int N, int K) {
    __shared__ unsigned short sA[TM * TK];   // 8 KB, row-major, no pad (DMA dest)
    __shared__ unsigned short sB[TN * TK];
    const int t = threadIdx.x;
    const int lane = t & 63;
    const int wave = t >> 6;
    const int wm = wave >> 1, wn = wave & 1;
    const int lq = lane >> 4;      // quad 0..3
    const int lr = lane & 15;
    const int bm = blockIdx.x * TM;
    const int bn = blockIdx.y * TN;

    f32x4 acc[4][4] = {};

    for (int k0 = 0; k0 < K; k0 += TK) {
        const unsigned short* Abase = A + (size_t)bm * K + k0;
        const unsigned short* Wbase = W + (size_t)bn * K + k0;
        #pragma unroll
        for (int j = 0; j < 2; ++j) {
            int chunk = j * 256 + t;                 // 16B chunk id
            int row = chunk >> 2, col = (chunk & 3) * 8;
            int wbase = j * 2048 + wave * 512;       // wave-uniform LDS elem offset
            g2l16(Abase + (size_t)row * K + col, sA + wbase);
            g2l16(Wbase + (size_t)row * K + col, sB + wbase);
        }
        __syncthreads();

        bf16x8 af[4], bfr[4];
        #pragma unroll
        for (int i = 0; i < 4; ++i)
            af[i] = *(const bf16x8*)&sA[(wm * 64 + i * 16 + lr) * TK + lq * 8];
        #pragma unroll
        for (int j = 0; j < 4; ++j)
            bfr[j] = *(const bf16x8*)&sB[(wn * 64 + j * 16 + lr) * TK + lq * 8];
        #pragma unroll
        for (int i = 0; i < 4; ++i)
            #pragma unroll
            for (int j = 0; j < 4; ++j)
                acc[i][j] = __builtin_amdgcn_mfma_f32_16x16x32_bf16(af[i], bfr[j], acc[i][j], 0, 0, 0);
        __syncthreads();
    }

    // epilogue: D row = quad*4 + reg, col = lane&15
    #pragma unroll
    for (int i = 0; i < 4; ++i) {
        int row0 = bm + wm * 64 + i * 16 + lq * 4;
        #pragma unroll
        for (int j = 0; j < 4; ++j) {
            int col = bn + wn * 64 + j * 16 + lr;
            const float* bp = col < E_ ? b0 : (col < 2 * E_ ? b1 : b2);
            float bv = bp[col & (E_ - 1)];
            #pragma unroll
            for (int r = 0; r < 4; ++r) {
                float v = acc[i][j][r] + bv;
                if (WRITE_F32) Cf[(size_t)(row0 + r) * N + col] = v;
                else           Cb[(size_t)(row0 + r) * N + col] = f2bf(v);
            }
        }
    }
}

// ---------------- sparse attention rows i >= 2 ----------------
__global__ __launch_bounds__(256)
void attn_sparse(const unsigned short* __restrict__ qkv,
                 const int* __restrict__ rnd,
                 unsigned short* __restrict__ attn) {
    int idx = blockIdx.x;                 // [0, B*(S-2))
    int b = idx / (S_ - 2);
    int i = idx % (S_ - 2) + 2;
    __shared__ int cols[16];
    __shared__ int ncol_s;
    __shared__ float sc[16][17];          // [h][c], padded
    __shared__ float qs[E_];              // q row (all heads), fp32
    int t = threadIdx.x;

    {   // coalesced q-row stage
        const ushort4* qp = (const ushort4*)(qkv + (size_t)(b * S_ + i) * 3072);
        ushort4 v = qp[t];
        qs[4 * t + 0] = bf2f(v.x); qs[4 * t + 1] = bf2f(v.y);
        qs[4 * t + 2] = bf2f(v.z); qs[4 * t + 3] = bf2f(v.w);
    }
    if (t == 0) {
        int n = 0;
        cols[n++] = 0; cols[n++] = 1;
        int lo = i - WIN; if (lo < 0) lo = 0;
        int hi = i + WIN; if (hi > S_ - 1) hi = S_ - 1;
        for (int j = lo; j <= hi; ++j) if (j >= NGLOB) cols[n++] = j;
        for (int r = 0; r < NRAND; ++r) {
            int c = rnd[i * NRAND + r];
            bool dup = false;
            for (int q = 0; q < n; ++q) dup = dup || (cols[q] == c);
            if (!dup) cols[n++] = c;
        }
        ncol_s = n;
    }
    __syncthreads();
    int n = ncol_s;
    int h = t >> 4, c = t & 15;

    if (c < n) {
        const bf16x8* kp = (const bf16x8*)(qkv + (size_t)(b * S_ + cols[c]) * 3072 + E_ + h * D_);
        float s = 0.f;
        #pragma unroll
        for (int w = 0; w < 8; ++w) {
            bf16x8 kv = kp[w];
            #pragma unroll
            for (int j = 0; j < 8; ++j) s += qs[h * D_ + w * 8 + j] * (float)kv[j];
        }
        sc[h][c] = s * 0.125f;
    }
    __syncthreads();
    if (t < H_) {
        float m = -1e30f;
        for (int cc = 0; cc < n; ++cc) m = fmaxf(m, sc[t][cc]);
        float sum = 0.f;
        for (int cc = 0; cc < n; ++cc) { float e = __expf(sc[t][cc] - m); sc[t][cc] = e; sum += e; }
        float inv = 1.f / sum;
        for (int cc = 0; cc < n; ++cc) sc[t][cc] *= inv;
    }
    __syncthreads();

    int d0 = (t & 15) * 4;
    float o0 = 0, o1 = 0, o2 = 0, o3 = 0;
    for (int cc = 0; cc < n; ++cc) {
        float p = sc[h][cc];
        ushort4 vv = *(const ushort4*)(qkv + (size_t)(b * S_ + cols[cc]) * 3072 + 2 * E_ + h * D_ + d0);
        o0 += p * bf2f(vv.x); o1 += p * bf2f(vv.y);
        o2 += p * bf2f(vv.z); o3 += p * bf2f(vv.w);
    }
    unsigned short* op = attn + (size_t)(b * S_ + i) * E_ + h * D_ + d0;
    op[0] = f2bf(o0); op[1] = f2bf(o1); op[2] = f2bf(o2); op[3] = f2bf(o3);
}

// ---------------- global rows (i < 2): phased, parallel ----------------
// tuple id: tup = b*32 + i*16 + h   (64 tuples)

__global__ __launch_bounds__(256)
void gattn_score(const unsigned short* __restrict__ qkv, float* __restrict__ gsc) {
    int tup = blockIdx.x;
    int b = tup >> 5, i = (tup >> 4) & 1, h = tup & 15;
    __shared__ float qs[D_];
    int t = threadIdx.x;
    if (t < D_) qs[t] = bf2f(qkv[(size_t)(b * S_ + i) * 3072 + h * D_ + t]);
    __syncthreads();
    int c = blockIdx.y * 256 + t;
    const bf16x8* kp = (const bf16x8*)(qkv + (size_t)(b * S_ + c) * 3072 + E_ + h * D_);
    float s = 0.f;
    #pragma unroll
    for (int w = 0; w < 8; ++w) {
        bf16x8 kv = kp[w];
        #pragma unroll
        for (int j = 0; j < 8; ++j) s += qs[w * 8 + j] * (float)kv[j];
    }
    gsc[(size_t)tup * S_ + c] = s * 0.125f;
}

__global__ __launch_bounds__(256)
void gattn_softmax(float* __restrict__ gsc, float* __restrict__ gacc) {
    int tup = blockIdx.x;
    int t = threadIdx.x;
    float* sc = gsc + (size_t)tup * S_;
    __shared__ float red[4];
    float vals[8];
    float m = -1e30f;
    #pragma unroll
    for (int k = 0; k < 8; ++k) { vals[k] = sc[t + 256 * k]; m = fmaxf(m, vals[k]); }
    #pragma unroll
    for (int o = 32; o; o >>= 1) m = fmaxf(m, __shfl_down(m, o));
    if ((t & 63) == 0) red[t >> 6] = m;
    __syncthreads();
    m = fmaxf(fmaxf(red[0], red[1]), fmaxf(red[2], red[3]));
    float sum = 0.f;
    #pragma unroll
    for (int k = 0; k < 8; ++k) { float e = __expf(vals[k] - m); vals[k] = e; sum += e; }
    #pragma unroll
    for (int o = 32; o; o >>= 1) sum += __shfl_down(sum, o);
    __syncthreads();
    if ((t & 63) == 0) red[t >> 6] = sum;
    __syncthreads();
    float inv = 1.f / (red[0] + red[1] + red[2] + red[3]);
    #pragma unroll
    for (int k = 0; k < 8; ++k) sc[t + 256 * k] = vals[k] * inv;
    if (t < D_) gacc[tup * D_ + t] = 0.f;
}

__global__ __launch_bounds__(256)
void gattn_pv(const unsigned short* __restrict__ qkv, const float* __restrict__ gsc,
              float* __restrict__ gacc) {
    int tup = blockIdx.x, chunk = blockIdx.y;
    int b = tup >> 5, h = tup & 15;
    int t = threadIdx.x, w = t >> 6, d = t & 63;
    __shared__ float red[4][D_];
    const float* P = gsc + (size_t)tup * S_ + chunk * 256 + w * 64;
    float acc = 0.f;
    #pragma unroll 4
    for (int k = 0; k < 64; ++k) {
        int c = chunk * 256 + w * 64 + k;
        acc += P[k] * bf2f(qkv[(size_t)(b * S_ + c) * 3072 + 2 * E_ + h * D_ + d]);
    }
    red[w][d] = acc;
    __syncthreads();
    if (w == 0)
        atomicAdd(&gacc[tup * D_ + d], red[0][d] + red[1][d] + red[2][d] + red[3][d]);
}

__global__ __launch_bounds__(256)
void gattn_fin(const float* __restrict__ gacc, unsigned short* __restrict__ attn) {
    int gid = blockIdx.x * 256 + threadIdx.x;   // 4096
    int tup = gid >> 6, d = gid & 63;
    int b = tup >> 5, i = (tup >> 4) & 1, h = tup & 15;
    attn[(size_t)(b * S_ + i) * E_ + h * D_ + d] = f2bf(gacc[gid]);
}

extern "C" void kernel_launch(void* const* d_in, const int* in_sizes, int n_in,
                              void* d_out, int out_size, void* d_ws, size_t ws_size,
                              hipStream_t stream) {
    const float* x   = (const float*)d_in[0];
    const int*   rnd = (const int*)d_in[1];
    const float* qw  = (const float*)d_in[2];
    const float* qb  = (const float*)d_in[3];
    const float* kw  = (const float*)d_in[4];
    const float* kb  = (const float*)d_in[5];
    const float* vw  = (const float*)d_in[6];
    const float* vb  = (const float*)d_in[7];
    const float* ow  = (const float*)d_in[8];
    const float* ob  = (const float*)d_in[9];
    float* out = (float*)d_out;

    char* ws = (char*)d_ws;
    unsigned short* xb    = (unsigned short*)(ws);                       // 8 MB (dead after QKV GEMM)
    unsigned short* wqkv  = (unsigned short*)(ws + 8388608);             // 6 MB
    unsigned short* wo    = (unsigned short*)(ws + 14680064);            // 2 MB
    unsigned short* qkv   = (unsigned short*)(ws + 16777216);            // 24 MB
    unsigned short* attn  = (unsigned short*)(ws + 41943040);            // 8 MB
    // global-attn scratch overlaps dead xb region:
    float*          gsc   = (float*)(ws);                                // 512 KB
    float*          gacc  = (float*)(ws + 524288);                       // 16 KB

    const int M = B_ * S_;   // 4096

    // conversions (1 launch)
    {
        int total4 = (M * E_ + 4 * E_ * E_) / 4;   // 2097152
        convert_all<<<total4 / 256, 256, 0, stream>>>(x, qw, kw, vw, ow, xb, wqkv, wo);
    }

    // QKV GEMM: [4096][3072] bf16
    {
        dim3 grid(M / TM, 3 * E_ / TN);
        gemm_bt<0><<<grid, 256, 0, stream>>>(xb, wqkv, qb, kb, vb, nullptr, qkv, M, 3 * E_, E_);
    }

    // global-row attention (phased)
    gattn_score<<<dim3(B_ * NGLOB * H_, S_ / 256), 256, 0, stream>>>(qkv, gsc);
    gattn_softmax<<<B_ * NGLOB * H_, 256, 0, stream>>>(gsc, gacc);
    gattn_pv<<<dim3(B_ * NGLOB * H_, S_ / 256), 256, 0, stream>>>(qkv, gsc, gacc);
    gattn_fin<<<(B_ * NGLOB * H_ * D_) / 256, 256, 0, stream>>>(gacc, attn);

    // sparse rows
    attn_sparse<<<B_ * (S_ - 2), 256, 0, stream>>>(qkv, rnd, attn);

    // O GEMM -> fp32 out
    {
        dim3 grid(M / TM, E_ / TN);
        gemm_bt<1><<<grid, 256, 0, stream>>>(attn, wo, ob, ob, ob, out, nullptr, M, E_, E_);
    }
}